// Round 11
// baseline (81.283 us; speedup 1.0000x reference)
//
#include <hip/hip_runtime.h>
#include <math.h>

#define N 512
#define TILE 32
#define TSTRIDE 34  // ts row stride in dwords: aligned float2 writes, 2-way-conflict reads (free)
#define INV2PI 0.15915494309189535f

// ---- packed (2-element-per-lane) float2 helpers ----
__device__ __forceinline__ float2 pset(float a, float b) { return make_float2(a, b); }
__device__ __forceinline__ float2 psplat(float a) { return make_float2(a, a); }
__device__ __forceinline__ float2 p_sub(float2 a, float2 b) { return make_float2(a.x - b.x, a.y - b.y); }
__device__ __forceinline__ float2 p_mul(float2 a, float2 b) { return make_float2(a.x * b.x, a.y * b.y); }
__device__ __forceinline__ float2 p_fma(float2 a, float2 b, float2 c) {
    return make_float2(fmaf(a.x, b.x, c.x), fmaf(a.y, b.y, c.y));
}
// a*b - c*d (fused)
__device__ __forceinline__ float2 p_fmsub(float2 a, float2 b, float2 c, float2 d) {
    return make_float2(fmaf(a.x, b.x, -(c.x * d.x)), fmaf(a.y, b.y, -(c.y * d.y)));
}
__device__ __forceinline__ float2 p_rsq(float2 a) {
    return make_float2(__builtin_amdgcn_rsqf(a.x), __builtin_amdgcn_rsqf(a.y));
}

struct F3P { float2 x, y, z; };

__device__ __forceinline__ F3P pp_sub(F3P a, F3P b) {
    return {p_sub(a.x, b.x), p_sub(a.y, b.y), p_sub(a.z, b.z)};
}
__device__ __forceinline__ F3P pp_cross(F3P a, F3P b) {
    F3P c;
    c.x = p_fmsub(a.y, b.z, a.z, b.y);
    c.y = p_fmsub(a.z, b.x, a.x, b.z);
    c.z = p_fmsub(a.x, b.y, a.y, b.x);
    return c;
}
__device__ __forceinline__ float2 pp_dot(F3P a, F3P b) {
    return p_fma(a.x, b.x, p_fma(a.y, b.y, p_mul(a.z, b.z)));
}

// Fused clamp + Abramowitz-Stegun 4.4.45 asin + sign restore. |err| <= 5e-5.
__device__ __forceinline__ float2 p_asin_clamped(float2 t) {
    float2 ax = make_float2(fminf(fabsf(t.x), 1.f), fminf(fabsf(t.y), 1.f));
    float2 p = p_fma(ax, psplat(-0.0187293f), psplat(0.0742610f));
    p = p_fma(ax, p, psplat(-0.2121144f));
    p = p_fma(ax, p, psplat(1.5707288f));
    float sx = __builtin_amdgcn_sqrtf(1.0f - ax.x);
    float sy = __builtin_amdgcn_sqrtf(1.0f - ax.y);
    float rx = fmaf(-sx, p.x, 1.5707963267948966f);
    float ry = fmaf(-sy, p.y, 1.5707963267948966f);
    return make_float2(copysignf(rx, t.x), copysignf(ry, t.y));
}

// Two independent writhe evaluations, one per float2 half.
// u=p1-p0, v=p3-p2, d0=p2-p0; c0=d0xv, c3=d0xu, w=uxv, c1=w-c3, c2=w-c0,
// sign dot: -cross(v,u).d0 = w.d0  (identities verified symbolically).
__device__ __forceinline__ float2 wr_core2(F3P p0, F3P p1, F3P p2, F3P p3) {
    F3P u = pp_sub(p1, p0);
    F3P v = pp_sub(p3, p2);
    F3P d0 = pp_sub(p2, p0);

    F3P c0 = pp_cross(d0, v);
    F3P c3 = pp_cross(d0, u);
    F3P w  = pp_cross(u, v);
    F3P c1 = {p_sub(w.x, c3.x), p_sub(w.y, c3.y), p_sub(w.z, c3.z)};
    F3P c2 = {p_sub(w.x, c0.x), p_sub(w.y, c0.y), p_sub(w.z, c0.z)};

    float2 svn = pp_dot(w, d0);  // sign(sv) = sign(-svn)

    float2 q0 = pp_dot(c0, c0);
    float2 q1 = pp_dot(c1, c1);
    float2 q2 = pp_dot(c2, c2);
    float2 q3 = pp_dot(c3, c3);

    float2 t01 = p_mul(pp_dot(c0, c1), p_rsq(p_mul(q0, q1)));
    float2 t12 = p_mul(pp_dot(c1, c2), p_rsq(p_mul(q1, q2)));
    float2 t23 = p_mul(pp_dot(c2, c3), p_rsq(p_mul(q2, q3)));
    float2 t30 = p_mul(pp_dot(c3, c0), p_rsq(p_mul(q3, q0)));

    float2 a01 = p_asin_clamped(t01), a12 = p_asin_clamped(t12);
    float2 a23 = p_asin_clamped(t23), a30 = p_asin_clamped(t30);
    float2 omega = make_float2(a01.x + a12.x + a23.x + a30.x,
                               a01.y + a12.y + a23.y + a30.y);

    float ox = __int_as_float(__float_as_int(omega.x) ^
                              (__float_as_int(svn.x) & 0x80000000));
    float oy = __int_as_float(__float_as_int(omega.y) ^
                              (__float_as_int(svn.y) & 0x80000000));
    return make_float2(ox * -INV2PI, oy * -INV2PI);
}

__device__ __forceinline__ F3P pack_pt4(float4 a, float4 b) {
    F3P r;
    r.x = pset(a.x, b.x);
    r.y = pset(a.y, b.y);
    r.z = pset(a.z, b.z);
    return r;
}
__device__ __forceinline__ F3P pack_pt(const float4* __restrict__ xs4, int i0, int i1) {
    return pack_pt4(xs4[i0], xs4[i1]);
}
__device__ __forceinline__ F3P splat_pt4(float4 a) {
    F3P r;
    r.x = psplat(a.x);
    r.y = psplat(a.y);
    r.z = psplat(a.z);
    return r;
}

// Branchless per-element index rule: out(lo,hi): lo>=1 & hi>=lo+2 -> segment
// (lo-1,hi-1); lo==0 & 2<=hi<=510 -> segment (0,hi). Clamped for speculative loads.
__device__ __forceinline__ void elem_idx(int gi, int gj, int& a, int& b, bool& valid) {
    const int lo = min(gi, gj), hi = max(gi, gj);
    const bool z = (lo == 0);
    a = z ? 0 : (lo - 1);
    b = z ? min(hi, 510) : (hi - 1);
    valid = z ? ((hi >= 2) && (hi <= 510)) : (hi >= lo + 2);
}

// One block (128 threads) per (upper-triangle tile pair, batch).
// Thread coarsening for ILP: 8 elements/thread = 4 packed wr_core2 calls = 8
// independent scalar dependency chains, with ALL point loads hoisted ahead of
// compute. Wave count halves vs 256-thread blocks; barriers sync 2 waves.
__global__ __launch_bounds__(128) void writhe_tile(const float* __restrict__ x,
                                                   float* __restrict__ out) {
    __shared__ __align__(16) float4 xs4[N];
    __shared__ __align__(16) float tsf[TILE * TSTRIDE];

    const int batch = blockIdx.y;

    // Coalesced float4 global read, stride-3 -> stride-4 repack into LDS.
    {
        const float4* src = (const float4*)(x + (size_t)batch * (N * 3));
        float* xsf = (float*)xs4;
        for (int i = threadIdx.x; i < (N * 3) / 4; i += blockDim.x) {
            float4 g = src[i];
            const int base = 4 * i;
            float vv[4] = {g.x, g.y, g.z, g.w};
#pragma unroll
            for (int j = 0; j < 4; ++j) {
                const int e = base + j;
                xsf[(e / 3) * 4 + (e % 3)] = vv[j];
            }
        }
    }

    // blockIdx.x -> (ti, tj), ti <= tj, among 16x16 tiles (136 pairs).
    int p = blockIdx.x;
    int ti = 0;
    while (p >= (N / TILE) - ti) { p -= (N / TILE) - ti; ++ti; }
    const int tj = ti + p;
    const bool diag = (ti == tj);

    __syncthreads();

    float* ob = out + (size_t)batch * (N * N);

    if (ti >= 1 && !diag) {
        // ---- fast path: index rule is unconditionally (gi-1, gj-1) ----
        const int cp = threadIdx.x & 15;  // column pair 0..15
        const int r = threadIdx.x >> 4;   // row base 0..7
        const int gj0 = tj * TILE + 2 * cp;

        // 3 unique column points (halves share xs4[gj0]).
        const float4 qa = xs4[gj0 - 1];
        const float4 qb = xs4[gj0];
        const float4 qc = xs4[gj0 + 1];
        const F3P P2 = pack_pt4(qa, qb);
        const F3P P3 = pack_pt4(qb, qc);

        // Hoist ALL row-point loads ahead of compute: 8 ds_read_b128, then the
        // 4 packed calls are pure-VALU and fully interleavable.
        float4 ra[4], rb[4];
#pragma unroll
        for (int k = 0; k < 4; ++k) {
            const int gi = ti * TILE + r + 8 * k;
            ra[k] = xs4[gi - 1];
            rb[k] = xs4[gi];
        }

#pragma unroll
        for (int k = 0; k < 4; ++k) {
            const int rr = r + 8 * k;
            const int gi = ti * TILE + rr;
            float2 wr = wr_core2(splat_pt4(ra[k]), splat_pt4(rb[k]), P2, P3);
            // Only gj0==gi+1 (adjacent tiles) can violate hi>=lo+2; gj0+1 never can.
            const float vx = (gj0 >= gi + 2) ? wr.x : 0.f;
            const float2 vv = make_float2(vx, wr.y);
            *(float2*)(ob + (size_t)gi * N + gj0) = vv;
            *(float2*)(tsf + rr * TSTRIDE + 2 * cp) = vv;
        }

        __syncthreads();
        // Transpose write: 2 x float4 per thread.
#pragma unroll
        for (int k = 0; k < 2; ++k) {
            const int r2 = threadIdx.x & 31;
            const int g = (threadIdx.x >> 5) + 4 * k;  // 0..7
            float4 o;
            o.x = tsf[(4 * g + 0) * TSTRIDE + r2];
            o.y = tsf[(4 * g + 1) * TSTRIDE + r2];
            o.z = tsf[(4 * g + 2) * TSTRIDE + r2];
            o.w = tsf[(4 * g + 3) * TSTRIDE + r2];
            *(float4*)(ob + (size_t)(tj * TILE + r2) * N + ti * TILE + 4 * g) = o;
        }
    } else {
        // ---- generic path (diag + ti==0 tiles): 8 elements/thread ----
        const int c = threadIdx.x & 31;
        const int r0 = threadIdx.x >> 5;  // 0..3
        const int gj = tj * TILE + c;

#pragma unroll
        for (int k = 0; k < 4; ++k) {
            const int rA = r0 + 4 * k;   // 0..15
            const int rB = rA + 16;      // 16..31
            const int giA = ti * TILE + rA;
            const int giB = ti * TILE + rB;

            int aA, bA, aB, bB;
            bool vA, vB;
            elem_idx(giA, gj, aA, bA, vA);
            elem_idx(giB, gj, aB, bB, vB);

            F3P P0 = pack_pt(xs4, aA, aB);
            F3P P1 = pack_pt(xs4, aA + 1, aB + 1);
            F3P P2 = pack_pt(xs4, bA, bB);
            F3P P3 = pack_pt(xs4, bA + 1, bB + 1);

            float2 wr = wr_core2(P0, P1, P2, P3);
            const float vxA = vA ? wr.x : 0.f;
            const float vxB = vB ? wr.y : 0.f;

            ob[(size_t)giA * N + gj] = vxA;
            ob[(size_t)giB * N + gj] = vxB;
            if (!diag) {
                tsf[rA * TSTRIDE + c] = vxA;
                tsf[rB * TSTRIDE + c] = vxB;
            }
        }

        if (!diag) {
            __syncthreads();
#pragma unroll
            for (int k = 0; k < 2; ++k) {
                const int r2 = threadIdx.x & 31;
                const int g = (threadIdx.x >> 5) + 4 * k;
                float4 o;
                o.x = tsf[(4 * g + 0) * TSTRIDE + r2];
                o.y = tsf[(4 * g + 1) * TSTRIDE + r2];
                o.z = tsf[(4 * g + 2) * TSTRIDE + r2];
                o.w = tsf[(4 * g + 3) * TSTRIDE + r2];
                *(float4*)(ob + (size_t)(tj * TILE + r2) * N + ti * TILE + 4 * g) = o;
            }
        }
    }
}

extern "C" void kernel_launch(void* const* d_in, const int* in_sizes, int n_in,
                              void* d_out, int out_size, void* d_ws, size_t ws_size,
                              hipStream_t stream) {
    const float* x = (const float*)d_in[0];
    float* out = (float*)d_out;
    const int B = in_sizes[0] / (N * 3);

    const int ntiles = N / TILE;                   // 16
    const int npairs = ntiles * (ntiles + 1) / 2;  // 136

    dim3 block(128);
    dim3 grid(npairs, B);
    writhe_tile<<<grid, block, 0, stream>>>(x, out);
}